// Round 1
// baseline (1233.059 us; speedup 1.0000x reference)
//
#include <hip/hip_runtime.h>
#include <hip/hip_bf16.h>

#define N_NODES 50000
#define N_EDGES 819200
#define NUM_RELS 8
#define EPR (N_EDGES / NUM_RELS) /* 102400 */
#define N_HEADS 4
#define IN_FEAT 256
#define OUT_FEAT 128
#define HEAD_DIM 32

// ---- workspace layout (float units) ----
#define SZ_FEAT ((size_t)NUM_RELS * N_NODES * OUT_FEAT) /* 51,200,000 */
#define SZ_EL ((size_t)NUM_RELS * N_NODES * N_HEADS)    /* 1,600,000 */
#define SZ_WB ((size_t)IN_FEAT * 64)                    /* 16,384 */
#define SZ_DEN ((size_t)N_NODES * N_HEADS)              /* 200,000 */
#define OFF_FEAT ((size_t)0)
#define OFF_EL (OFF_FEAT + SZ_FEAT)
#define OFF_ER (OFF_EL + SZ_EL)
#define OFF_WB (OFF_ER + SZ_EL)
#define OFF_DEN (OFF_WB + SZ_WB)

// wboth[i][col]: col = side*32 + r*4 + h; wl/wr folded attention vectors:
// wboth[i][side,r,h] = sum_d cw[r,h,i,d] * attn_{l|r}[r,h,d]
__global__ void k_wboth(const float* __restrict__ cw, const float* __restrict__ al,
                        const float* __restrict__ ar, float* __restrict__ wboth) {
    int tid = blockIdx.x * blockDim.x + threadIdx.x; // 16384 total
    if (tid >= IN_FEAT * 64) return;
    int i = tid >> 6, col = tid & 63;
    int side = col >> 5, r = (col >> 2) & 7, h = col & 3;
    const float* av = (side ? ar : al) + (size_t)(r * N_HEADS + h) * HEAD_DIM;
    const float* cwp = cw + ((size_t)(r * N_HEADS + h) * IN_FEAT + i) * HEAD_DIM;
    float s = 0.f;
#pragma unroll
    for (int d = 0; d < HEAD_DIM; ++d) s += cwp[d] * av[d];
    wboth[(size_t)i * 64 + col] = s;
}

// feat_all[r][n][o] = sum_k x[n][k] * cw[r][o>>5][k][o&31]
// tile: 32 nodes x 128 outs, K=256 (A fully staged, B in 4 chunks of 64)
__global__ __launch_bounds__(256) void k_transform(const float* __restrict__ x,
                                                   const float* __restrict__ cw,
                                                   float* __restrict__ feat) {
    __shared__ float As[32][IN_FEAT];   // 32 KB
    __shared__ float Bs[64][OUT_FEAT];  // 32 KB
    const int t = threadIdx.x;
    const int n0 = blockIdx.x * 32;
    const int r = blockIdx.y;

    // stage A: 32 rows x 256 k  (2048 float4 slots? no: 8192 floats = 2048 f4)
#pragma unroll
    for (int j = 0; j < 8; ++j) {
        int s = t + j * 256;         // 0..2047 float4 slots
        int row = s >> 6;            // 0..31
        int kq = s & 63;             // 0..63  (k = kq*4)
        int n = n0 + row;
        float4 v = make_float4(0.f, 0.f, 0.f, 0.f);
        if (n < N_NODES) v = *(const float4*)(x + (size_t)n * IN_FEAT + kq * 4);
        *(float4*)&As[row][kq * 4] = v;
    }

    float acc[4][4];
#pragma unroll
    for (int i = 0; i < 4; ++i)
#pragma unroll
        for (int j = 0; j < 4; ++j) acc[i][j] = 0.f;

    const int rg = t >> 5;  // 0..7  (rows rg*4..rg*4+3)
    const int cg = t & 31;  // 0..31 (cols cg*4..cg*4+3)
    const float* cwr = cw + (size_t)r * N_HEADS * IN_FEAT * HEAD_DIM;

    for (int kc = 0; kc < 4; ++kc) {
        const int k0 = kc * 64;
        // stage B chunk: 64 k-rows x 128 outs
#pragma unroll
        for (int j = 0; j < 8; ++j) {
            int s4 = t + j * 256;    // 0..2047 float4 slots
            int kk = s4 >> 5;        // 0..63
            int o0 = (s4 & 31) * 4;  // 0..124
            int h = o0 >> 5, d0 = o0 & 31;
            float4 v = *(const float4*)(cwr + ((size_t)h * IN_FEAT + (k0 + kk)) * HEAD_DIM + d0);
            *(float4*)&Bs[kk][o0] = v;
        }
        __syncthreads();
#pragma unroll 8
        for (int k = 0; k < 64; ++k) {
            float4 b = *(const float4*)&Bs[k][cg * 4];
#pragma unroll
            for (int i = 0; i < 4; ++i) {
                float a = As[rg * 4 + i][k0 + k];
                acc[i][0] += a * b.x;
                acc[i][1] += a * b.y;
                acc[i][2] += a * b.z;
                acc[i][3] += a * b.w;
            }
        }
        __syncthreads();
    }

#pragma unroll
    for (int i = 0; i < 4; ++i) {
        int n = n0 + rg * 4 + i;
        if (n < N_NODES) {
            float4 v = make_float4(acc[i][0], acc[i][1], acc[i][2], acc[i][3]);
            *(float4*)(feat + ((size_t)r * N_NODES + n) * OUT_FEAT + cg * 4) = v;
        }
    }
}

// el_all/er_all for ALL (r,n,h): one wave per node, lane = side*32 + r*4 + h
__global__ __launch_bounds__(256) void k_elr(const float* __restrict__ x,
                                             const float* __restrict__ wboth,
                                             float* __restrict__ el,
                                             float* __restrict__ er) {
    __shared__ float Xs[4][IN_FEAT];
    const int w = threadIdx.x >> 6, lane = threadIdx.x & 63;
    const int n = blockIdx.x * 4 + w;
    if (n < N_NODES) {
        float4 v = *(const float4*)(x + (size_t)n * IN_FEAT + lane * 4);
        *(float4*)&Xs[w][lane * 4] = v;
    }
    __syncthreads();
    if (n >= N_NODES) return;
    float acc = 0.f;
#pragma unroll 8
    for (int i = 0; i < IN_FEAT; ++i) acc += Xs[w][i] * wboth[(size_t)i * 64 + lane];
    int side = lane >> 5, r = (lane >> 2) & 7, h = lane & 3;
    float* dst = side ? er : el;
    dst[((size_t)r * N_NODES + n) * N_HEADS + h] = acc;
}

// one wave per edge: w = exp(leaky(el[r,row,h]+er[r,col,h]));
// denom[col,h] += w; out[col,:] += w * feat_all[r,row,:]
__global__ __launch_bounds__(256) void k_edge(const int* __restrict__ row_idx,
                                              const int* __restrict__ col_idx,
                                              const float* __restrict__ el,
                                              const float* __restrict__ er,
                                              const float* __restrict__ feat,
                                              float* __restrict__ denom,
                                              float* __restrict__ out) {
    const int wv = threadIdx.x >> 6, lane = threadIdx.x & 63;
    const int e = blockIdx.x * 4 + wv;
    if (e >= N_EDGES) return;
    const int r = e / EPR;
    const int row = row_idx[e], col = col_idx[e];
    const int h = lane >> 4;  // o = lane*2, head = o>>5 = lane>>4
    float s = el[((size_t)r * N_NODES + row) * N_HEADS + h] +
              er[((size_t)r * N_NODES + col) * N_HEADS + h];
    s = s > 0.f ? s : 0.2f * s;
    float wgt = __expf(s);
    // lanes 0..3 add denom for head=lane (value computed by lane 16*head)
    float wh = __shfl(wgt, (lane & 3) << 4);
    if (lane < 4) atomicAdd(denom + (size_t)col * N_HEADS + lane, wh);
    float2 v = *(const float2*)(feat + ((size_t)r * N_NODES + row) * OUT_FEAT + lane * 2);
    float* op = out + (size_t)col * OUT_FEAT + lane * 2;
    atomicAdd(op, wgt * v.x);
    atomicAdd(op + 1, wgt * v.y);
}

// out = (denom>0) ? acc/denom + bias : bias   (empty node -> bias, as reference)
__global__ void k_final(float* __restrict__ out, const float* __restrict__ denom,
                        const float* __restrict__ bias) {
    int idx = blockIdx.x * blockDim.x + threadIdx.x;
    if (idx >= N_NODES * OUT_FEAT) return;
    int n = idx >> 7, o = idx & 127, h = o >> 5;
    float d = denom[(size_t)n * N_HEADS + h];
    float a = out[idx];
    float b = bias[o];
    out[idx] = d > 0.f ? a / d + b : b;
}

extern "C" void kernel_launch(void* const* d_in, const int* in_sizes, int n_in,
                              void* d_out, int out_size, void* d_ws, size_t ws_size,
                              hipStream_t stream) {
    const float* x = (const float*)d_in[0];
    const float* cw = (const float*)d_in[1];
    const float* al = (const float*)d_in[2];
    const float* ar = (const float*)d_in[3];
    const float* bias = (const float*)d_in[4];
    const int* row = (const int*)d_in[5];
    const int* col = (const int*)d_in[6];
    float* out = (float*)d_out;
    float* ws = (float*)d_ws;

    float* feat = ws + OFF_FEAT;
    float* el = ws + OFF_EL;
    float* er = ws + OFF_ER;
    float* wb = ws + OFF_WB;
    float* den = ws + OFF_DEN;

    hipMemsetAsync(out, 0, (size_t)N_NODES * OUT_FEAT * sizeof(float), stream);
    hipMemsetAsync(den, 0, SZ_DEN * sizeof(float), stream);

    k_wboth<<<(IN_FEAT * 64 + 255) / 256, 256, 0, stream>>>(cw, al, ar, wb);
    k_transform<<<dim3((N_NODES + 31) / 32, NUM_RELS), 256, 0, stream>>>(x, cw, feat);
    k_elr<<<(N_NODES + 3) / 4, 256, 0, stream>>>(x, wb, el, er);
    k_edge<<<N_EDGES / 4, 256, 0, stream>>>(row, col, el, er, feat, den, out);
    k_final<<<(N_NODES * OUT_FEAT) / 256, 256, 0, stream>>>(out, den, bias);
}

// Round 2
// 671.042 us; speedup vs baseline: 1.8375x; 1.8375x over previous
//
#include <hip/hip_runtime.h>
#include <hip/hip_bf16.h>

#define N_NODES 50000
#define N_EDGES 819200
#define NUM_RELS 8
#define EPR (N_EDGES / NUM_RELS) /* 102400 */
#define N_HEADS 4
#define IN_FEAT 256
#define OUT_FEAT 128
#define HEAD_DIM 32
#define NB_SCAN ((N_NODES + 255) / 256) /* 196 */

// ---- workspace layout ----
// float region
#define SZ_FEAT ((size_t)NUM_RELS * N_NODES * OUT_FEAT) /* 51,200,000 */
#define SZ_EL ((size_t)NUM_RELS * N_NODES * N_HEADS)    /* 1,600,000 */
#define SZ_WB ((size_t)IN_FEAT * 64)                    /* 16,384 */
#define OFF_FEAT ((size_t)0)
#define OFF_EL (OFF_FEAT + SZ_FEAT)
#define OFF_ER (OFF_EL + SZ_EL)
#define OFF_WB (OFF_ER + SZ_EL)
#define OFF_INT (OFF_WB + SZ_WB)
// int region (offsets in ints, from OFF_INT)
#define IOFF_CNT ((size_t)0)
#define IOFF_PTR ((size_t)N_NODES)
#define IOFF_CUR ((size_t)2 * N_NODES)
#define IOFF_BSUM ((size_t)3 * N_NODES)
#define IOFF_SPAY ((size_t)3 * N_NODES + 256)

// wboth[i][col]: col = side*32 + r*4 + h; folded attention vectors:
// wboth[i][side,r,h] = sum_d cw[r,h,i,d] * attn_{l|r}[r,h,d]
__global__ void k_wboth(const float* __restrict__ cw, const float* __restrict__ al,
                        const float* __restrict__ ar, float* __restrict__ wboth) {
    int tid = blockIdx.x * blockDim.x + threadIdx.x; // 16384 total
    if (tid >= IN_FEAT * 64) return;
    int i = tid >> 6, col = tid & 63;
    int side = col >> 5, r = (col >> 2) & 7, h = col & 3;
    const float* av = (side ? ar : al) + (size_t)(r * N_HEADS + h) * HEAD_DIM;
    const float* cwp = cw + ((size_t)(r * N_HEADS + h) * IN_FEAT + i) * HEAD_DIM;
    float s = 0.f;
#pragma unroll
    for (int d = 0; d < HEAD_DIM; ++d) s += cwp[d] * av[d];
    wboth[(size_t)i * 64 + col] = s;
}

// feat_all[r][n][o] = sum_k x[n][k] * cw[r][o>>5][k][o&31]
__global__ __launch_bounds__(256) void k_transform(const float* __restrict__ x,
                                                   const float* __restrict__ cw,
                                                   float* __restrict__ feat) {
    __shared__ float As[32][IN_FEAT];   // 32 KB
    __shared__ float Bs[64][OUT_FEAT];  // 32 KB
    const int t = threadIdx.x;
    const int n0 = blockIdx.x * 32;
    const int r = blockIdx.y;

#pragma unroll
    for (int j = 0; j < 8; ++j) {
        int s = t + j * 256;
        int row = s >> 6;
        int kq = s & 63;
        int n = n0 + row;
        float4 v = make_float4(0.f, 0.f, 0.f, 0.f);
        if (n < N_NODES) v = *(const float4*)(x + (size_t)n * IN_FEAT + kq * 4);
        *(float4*)&As[row][kq * 4] = v;
    }

    float acc[4][4];
#pragma unroll
    for (int i = 0; i < 4; ++i)
#pragma unroll
        for (int j = 0; j < 4; ++j) acc[i][j] = 0.f;

    const int rg = t >> 5;
    const int cg = t & 31;
    const float* cwr = cw + (size_t)r * N_HEADS * IN_FEAT * HEAD_DIM;

    for (int kc = 0; kc < 4; ++kc) {
        const int k0 = kc * 64;
#pragma unroll
        for (int j = 0; j < 8; ++j) {
            int s4 = t + j * 256;
            int kk = s4 >> 5;
            int o0 = (s4 & 31) * 4;
            int h = o0 >> 5, d0 = o0 & 31;
            float4 v = *(const float4*)(cwr + ((size_t)h * IN_FEAT + (k0 + kk)) * HEAD_DIM + d0);
            *(float4*)&Bs[kk][o0] = v;
        }
        __syncthreads();
#pragma unroll 8
        for (int k = 0; k < 64; ++k) {
            float4 b = *(const float4*)&Bs[k][cg * 4];
#pragma unroll
            for (int i = 0; i < 4; ++i) {
                float a = As[rg * 4 + i][k0 + k];
                acc[i][0] += a * b.x;
                acc[i][1] += a * b.y;
                acc[i][2] += a * b.z;
                acc[i][3] += a * b.w;
            }
        }
        __syncthreads();
    }

#pragma unroll
    for (int i = 0; i < 4; ++i) {
        int n = n0 + rg * 4 + i;
        if (n < N_NODES) {
            float4 v = make_float4(acc[i][0], acc[i][1], acc[i][2], acc[i][3]);
            *(float4*)(feat + ((size_t)r * N_NODES + n) * OUT_FEAT + cg * 4) = v;
        }
    }
}

// el/er for ALL (r,n,h): one wave per node, lane = side*32 + r*4 + h
__global__ __launch_bounds__(256) void k_elr(const float* __restrict__ x,
                                             const float* __restrict__ wboth,
                                             float* __restrict__ el,
                                             float* __restrict__ er) {
    __shared__ float Xs[4][IN_FEAT];
    const int w = threadIdx.x >> 6, lane = threadIdx.x & 63;
    const int n = blockIdx.x * 4 + w;
    if (n < N_NODES) {
        float4 v = *(const float4*)(x + (size_t)n * IN_FEAT + lane * 4);
        *(float4*)&Xs[w][lane * 4] = v;
    }
    __syncthreads();
    if (n >= N_NODES) return;
    float acc = 0.f;
#pragma unroll 8
    for (int i = 0; i < IN_FEAT; ++i) acc += Xs[w][i] * wboth[(size_t)i * 64 + lane];
    int side = lane >> 5, r = (lane >> 2) & 7, h = lane & 3;
    float* dst = side ? er : el;
    dst[((size_t)r * N_NODES + n) * N_HEADS + h] = acc;
}

// ---- CSR build: histogram -> exclusive scan (2-level) -> scatter ----
__global__ void k_hist(const int* __restrict__ col, int* __restrict__ cnt) {
    int e = blockIdx.x * blockDim.x + threadIdx.x;
    if (e < N_EDGES) atomicAdd(cnt + col[e], 1);
}

__global__ __launch_bounds__(256) void k_scanA(const int* __restrict__ cnt,
                                               int* __restrict__ excl,
                                               int* __restrict__ bsum) {
    __shared__ int s[256];
    int i = blockIdx.x * 256 + threadIdx.x;
    int v = (i < N_NODES) ? cnt[i] : 0;
    s[threadIdx.x] = v;
    __syncthreads();
#pragma unroll
    for (int off = 1; off < 256; off <<= 1) {
        int t = (threadIdx.x >= off) ? s[threadIdx.x - off] : 0;
        __syncthreads();
        s[threadIdx.x] += t;
        __syncthreads();
    }
    if (i < N_NODES) excl[i] = s[threadIdx.x] - v;
    if (threadIdx.x == 255) bsum[blockIdx.x] = s[255];
}

__global__ __launch_bounds__(256) void k_scanB(int* __restrict__ bsum) {
    __shared__ int s[256];
    int v = (threadIdx.x < NB_SCAN) ? bsum[threadIdx.x] : 0;
    s[threadIdx.x] = v;
    __syncthreads();
#pragma unroll
    for (int off = 1; off < 256; off <<= 1) {
        int t = (threadIdx.x >= off) ? s[threadIdx.x - off] : 0;
        __syncthreads();
        s[threadIdx.x] += t;
        __syncthreads();
    }
    bsum[threadIdx.x] = s[threadIdx.x] - v; // exclusive
}

__global__ __launch_bounds__(256) void k_scanC(int* __restrict__ ptr,
                                               int* __restrict__ cursor,
                                               const int* __restrict__ bsum) {
    int i = blockIdx.x * 256 + threadIdx.x;
    if (i >= N_NODES) return;
    int p = ptr[i] + bsum[blockIdx.x];
    ptr[i] = p;
    cursor[i] = p;
}

// spay[pos] = row | (r<<20)
__global__ void k_scatter(const int* __restrict__ row, const int* __restrict__ col,
                          int* __restrict__ cursor, int* __restrict__ spay) {
    int e = blockIdx.x * blockDim.x + threadIdx.x;
    if (e >= N_EDGES) return;
    int c = col[e];
    int pos = atomicAdd(cursor + c, 1);
    spay[pos] = row[e] | ((e / EPR) << 20);
}

// pull-aggregation: one wave per dst node, float2 per lane (128 outs),
// denom accumulated in-register; zero atomics, fused finalize.
__global__ __launch_bounds__(256) void k_agg(const int* __restrict__ ptr,
                                             const int* __restrict__ cnt,
                                             const int* __restrict__ spay,
                                             const float* __restrict__ el,
                                             const float* __restrict__ er,
                                             const float* __restrict__ feat,
                                             const float* __restrict__ bias,
                                             float* __restrict__ out) {
    const int wv = threadIdx.x >> 6, lane = threadIdx.x & 63;
    const int n = blockIdx.x * 4 + wv;
    if (n >= N_NODES) return;
    const int start = ptr[n], len = cnt[n];
    const int h = lane >> 4; // o = lane*2 -> head = o>>5
    float accx = 0.f, accy = 0.f, den = 0.f;
#pragma unroll 2
    for (int j = 0; j < len; ++j) {
        int p = spay[start + j];
        int rw = p & 0xFFFFF, r = p >> 20;
        size_t rb = (size_t)r * N_NODES;
        float s = el[(rb + rw) * N_HEADS + h] + er[(rb + n) * N_HEADS + h];
        s = s > 0.f ? s : 0.2f * s;
        float w = __expf(s);
        float2 v = *(const float2*)(feat + (rb + rw) * OUT_FEAT + lane * 2);
        accx += w * v.x;
        accy += w * v.y;
        den += w;
    }
    float inv = (len > 0) ? 1.f / den : 0.f;
    int o = lane * 2;
    float2 res;
    res.x = accx * inv + bias[o];
    res.y = accy * inv + bias[o + 1];
    *(float2*)(out + (size_t)n * OUT_FEAT + o) = res;
}

extern "C" void kernel_launch(void* const* d_in, const int* in_sizes, int n_in,
                              void* d_out, int out_size, void* d_ws, size_t ws_size,
                              hipStream_t stream) {
    const float* x = (const float*)d_in[0];
    const float* cw = (const float*)d_in[1];
    const float* al = (const float*)d_in[2];
    const float* ar = (const float*)d_in[3];
    const float* bias = (const float*)d_in[4];
    const int* row = (const int*)d_in[5];
    const int* col = (const int*)d_in[6];
    float* out = (float*)d_out;
    float* ws = (float*)d_ws;

    float* feat = ws + OFF_FEAT;
    float* el = ws + OFF_EL;
    float* er = ws + OFF_ER;
    float* wb = ws + OFF_WB;
    int* iw = (int*)(ws + OFF_INT);
    int* cnt = iw + IOFF_CNT;
    int* ptr = iw + IOFF_PTR;
    int* cur = iw + IOFF_CUR;
    int* bsum = iw + IOFF_BSUM;
    int* spay = iw + IOFF_SPAY;

    hipMemsetAsync(cnt, 0, N_NODES * sizeof(int), stream);

    k_wboth<<<(IN_FEAT * 64 + 255) / 256, 256, 0, stream>>>(cw, al, ar, wb);
    k_transform<<<dim3((N_NODES + 31) / 32, NUM_RELS), 256, 0, stream>>>(x, cw, feat);
    k_elr<<<(N_NODES + 3) / 4, 256, 0, stream>>>(x, wb, el, er);

    k_hist<<<(N_EDGES + 255) / 256, 256, 0, stream>>>(col, cnt);
    k_scanA<<<NB_SCAN, 256, 0, stream>>>(cnt, ptr, bsum);
    k_scanB<<<1, 256, 0, stream>>>(bsum);
    k_scanC<<<NB_SCAN, 256, 0, stream>>>(ptr, cur, bsum);
    k_scatter<<<(N_EDGES + 255) / 256, 256, 0, stream>>>(row, col, cur, spay);

    k_agg<<<(N_NODES + 3) / 4, 256, 0, stream>>>(ptr, cnt, spay, el, er, feat, bias, out);
}

// Round 3
// 383.176 us; speedup vs baseline: 3.2180x; 1.7513x over previous
//
#include <hip/hip_runtime.h>
#include <hip/hip_bf16.h>

#define N_NODES 50000
#define N_EDGES 819200
#define NUM_RELS 8
#define EPR (N_EDGES / NUM_RELS) /* 102400 */
#define N_HEADS 4
#define IN_FEAT 256
#define OUT_FEAT 128
#define HEAD_DIM 32
#define NB_SCAN ((N_NODES + 255) / 256) /* 196 */

typedef __attribute__((ext_vector_type(8))) __bf16 bf16x8;
typedef __attribute__((ext_vector_type(4))) __bf16 bf16x4;
typedef __attribute__((ext_vector_type(4))) float f32x4;

// ---- workspace layout ----
// float region
#define SZ_FEAT ((size_t)NUM_RELS * N_NODES * OUT_FEAT) /* 51,200,000 */
#define SZ_EL ((size_t)NUM_RELS * N_NODES * N_HEADS)    /* 1,600,000 */
#define SZ_WB ((size_t)IN_FEAT * 64)                    /* 16,384 */
#define SZ_WT ((size_t)NUM_RELS * OUT_FEAT * IN_FEAT / 2) /* 131,072 floats = 262144 bf16 */
#define OFF_FEAT ((size_t)0)
#define OFF_EL (OFF_FEAT + SZ_FEAT)
#define OFF_ER (OFF_EL + SZ_EL)
#define OFF_WB (OFF_ER + SZ_EL)
#define OFF_WT (OFF_WB + SZ_WB)
#define OFF_INT (OFF_WT + SZ_WT)
// int region (offsets in ints, from OFF_INT)
#define IOFF_CNT ((size_t)0)
#define IOFF_PTR ((size_t)N_NODES)
#define IOFF_CUR ((size_t)2 * N_NODES)
#define IOFF_BSUM ((size_t)3 * N_NODES)
#define IOFF_SPAY ((size_t)3 * N_NODES + 256)

// wboth[i][col]: col = side*32 + r*4 + h; folded attention vectors (fp32, exact logits)
__global__ void k_wboth(const float* __restrict__ cw, const float* __restrict__ al,
                        const float* __restrict__ ar, float* __restrict__ wboth) {
    int tid = blockIdx.x * blockDim.x + threadIdx.x; // 16384 total
    if (tid >= IN_FEAT * 64) return;
    int i = tid >> 6, col = tid & 63;
    int side = col >> 5, r = (col >> 2) & 7, h = col & 3;
    const float* av = (side ? ar : al) + (size_t)(r * N_HEADS + h) * HEAD_DIM;
    const float* cwp = cw + ((size_t)(r * N_HEADS + h) * IN_FEAT + i) * HEAD_DIM;
    float s = 0.f;
#pragma unroll
    for (int d = 0; d < HEAD_DIM; ++d) s += cwp[d] * av[d];
    wboth[(size_t)i * 64 + col] = s;
}

// wt[r][o][k] = bf16(cw[r][h][k][d]), o = h*32+d  -> B-operand k-contiguous
__global__ void k_cvt_w(const float* __restrict__ cw, __bf16* __restrict__ wt) {
    int tid = blockIdx.x * blockDim.x + threadIdx.x;
    if (tid >= NUM_RELS * N_HEADS * IN_FEAT * HEAD_DIM) return;
    int d = tid & 31, k = (tid >> 5) & 255, h = (tid >> 13) & 3, r = tid >> 15;
    float v = cw[tid]; // cw flat [r][h][k][d] == tid decomposition
    wt[((size_t)(r * OUT_FEAT + h * HEAD_DIM + d)) * IN_FEAT + k] = (__bf16)v;
}

// feat_all[r][n][o] = sum_k x[n][k]*W_r[k][o] via bf16 MFMA (fp32 accumulate)
// 128x128 tile, 4 waves (2x2), BK=64, XOR-swizzled LDS (16B slots, slot ^= row&7)
__global__ __launch_bounds__(256) void k_tmfma(const float* __restrict__ x,
                                               const __bf16* __restrict__ wt,
                                               float* __restrict__ feat) {
    __shared__ __align__(16) unsigned char sA[16384]; // [128 rows][64 k] bf16 swizzled
    __shared__ __align__(16) unsigned char sB[16384]; // [128 o  ][64 k] bf16 swizzled
    const int t = threadIdx.x;
    const int lane = t & 63, w = t >> 6;
    const int n0 = blockIdx.x * 128;
    const int r = blockIdx.y;
    const int wr = w >> 1, wc = w & 1;

    f32x4 acc[4][4];
#pragma unroll
    for (int i = 0; i < 4; ++i)
#pragma unroll
        for (int j = 0; j < 4; ++j) acc[i][j] = (f32x4){0.f, 0.f, 0.f, 0.f};

    const __bf16* wtr = wt + (size_t)r * OUT_FEAT * IN_FEAT;

    for (int kc = 0; kc < 4; ++kc) {
        // stage A: wave w covers rows w*32..+31; fp32 -> bf16, swizzled 8B writes
#pragma unroll
        for (int i = 0; i < 8; ++i) {
            int flat = i * 64 + lane;       // 0..511
            int row = w * 32 + (flat >> 4); // 16 lanes per row
            int kq = flat & 15;             // k = kq*4
            int nsrc = n0 + row;
            if (nsrc >= N_NODES) nsrc = N_NODES - 1;
            float4 v = *(const float4*)(x + (size_t)nsrc * IN_FEAT + kc * 64 + kq * 4);
            bf16x4 hv;
            hv[0] = (__bf16)v.x; hv[1] = (__bf16)v.y; hv[2] = (__bf16)v.z; hv[3] = (__bf16)v.w;
            int slot = (kq >> 1) ^ (row & 7);
            *(bf16x4*)(sA + row * 128 + slot * 16 + (kq & 1) * 8) = hv;
        }
        // stage B: bf16 16B slots, pre-swizzled source slot (involution)
#pragma unroll
        for (int i = 0; i < 4; ++i) {
            int flat = i * 64 + lane;      // 0..255
            int row = w * 32 + (flat >> 3);
            int s = flat & 7;
            int ssrc = s ^ (row & 7);
            bf16x8 v = *(const bf16x8*)(wtr + (size_t)row * IN_FEAT + kc * 64 + ssrc * 8);
            *(bf16x8*)(sB + row * 128 + s * 16) = v;
        }
        __syncthreads();
#pragma unroll
        for (int ks = 0; ks < 2; ++ks) {
            bf16x8 af[4], bg[4];
#pragma unroll
            for (int rb = 0; rb < 4; ++rb) {
                int row = wr * 64 + rb * 16 + (lane & 15);
                int slot = (ks * 4 + (lane >> 4)) ^ (row & 7);
                af[rb] = *(const bf16x8*)(sA + row * 128 + slot * 16);
            }
#pragma unroll
            for (int cb = 0; cb < 4; ++cb) {
                int row = wc * 64 + cb * 16 + (lane & 15);
                int slot = (ks * 4 + (lane >> 4)) ^ (row & 7);
                bg[cb] = *(const bf16x8*)(sB + row * 128 + slot * 16);
            }
#pragma unroll
            for (int rb = 0; rb < 4; ++rb)
#pragma unroll
                for (int cb = 0; cb < 4; ++cb)
                    acc[rb][cb] = __builtin_amdgcn_mfma_f32_16x16x32_bf16(af[rb], bg[cb], acc[rb][cb], 0, 0, 0);
        }
        __syncthreads();
    }
    // C write: col = lane&15, row = (lane>>4)*4 + q (m89-verified mapping)
#pragma unroll
    for (int rb = 0; rb < 4; ++rb) {
#pragma unroll
        for (int q = 0; q < 4; ++q) {
            int row = wr * 64 + rb * 16 + (lane >> 4) * 4 + q;
            int n = n0 + row;
            if (n < N_NODES) {
                float* fp = feat + ((size_t)r * N_NODES + n) * OUT_FEAT + wc * 64 + (lane & 15);
#pragma unroll
                for (int cb = 0; cb < 4; ++cb) fp[cb * 16] = acc[rb][cb][q];
            }
        }
    }
}

// el/er for ALL (r,n,h): one wave per node, lane = side*32 + r*4 + h (fp32)
__global__ __launch_bounds__(256) void k_elr(const float* __restrict__ x,
                                             const float* __restrict__ wboth,
                                             float* __restrict__ el,
                                             float* __restrict__ er) {
    __shared__ float Xs[4][IN_FEAT];
    const int w = threadIdx.x >> 6, lane = threadIdx.x & 63;
    const int n = blockIdx.x * 4 + w;
    if (n < N_NODES) {
        float4 v = *(const float4*)(x + (size_t)n * IN_FEAT + lane * 4);
        *(float4*)&Xs[w][lane * 4] = v;
    }
    __syncthreads();
    if (n >= N_NODES) return;
    float acc = 0.f;
#pragma unroll 8
    for (int i = 0; i < IN_FEAT; ++i) acc += Xs[w][i] * wboth[(size_t)i * 64 + lane];
    int side = lane >> 5, r = (lane >> 2) & 7, h = lane & 3;
    float* dst = side ? er : el;
    dst[((size_t)r * N_NODES + n) * N_HEADS + h] = acc;
}

// ---- CSR build: histogram -> exclusive scan (2-level) -> scatter ----
__global__ void k_hist(const int* __restrict__ col, int* __restrict__ cnt) {
    int e = blockIdx.x * blockDim.x + threadIdx.x;
    if (e < N_EDGES) atomicAdd(cnt + col[e], 1);
}

__global__ __launch_bounds__(256) void k_scanA(const int* __restrict__ cnt,
                                               int* __restrict__ excl,
                                               int* __restrict__ bsum) {
    __shared__ int s[256];
    int i = blockIdx.x * 256 + threadIdx.x;
    int v = (i < N_NODES) ? cnt[i] : 0;
    s[threadIdx.x] = v;
    __syncthreads();
#pragma unroll
    for (int off = 1; off < 256; off <<= 1) {
        int t = (threadIdx.x >= off) ? s[threadIdx.x - off] : 0;
        __syncthreads();
        s[threadIdx.x] += t;
        __syncthreads();
    }
    if (i < N_NODES) excl[i] = s[threadIdx.x] - v;
    if (threadIdx.x == 255) bsum[blockIdx.x] = s[255];
}

__global__ __launch_bounds__(256) void k_scanB(int* __restrict__ bsum) {
    __shared__ int s[256];
    int v = (threadIdx.x < NB_SCAN) ? bsum[threadIdx.x] : 0;
    s[threadIdx.x] = v;
    __syncthreads();
#pragma unroll
    for (int off = 1; off < 256; off <<= 1) {
        int t = (threadIdx.x >= off) ? s[threadIdx.x - off] : 0;
        __syncthreads();
        s[threadIdx.x] += t;
        __syncthreads();
    }
    bsum[threadIdx.x] = s[threadIdx.x] - v; // exclusive
}

__global__ __launch_bounds__(256) void k_scanC(int* __restrict__ ptr,
                                               int* __restrict__ cursor,
                                               const int* __restrict__ bsum) {
    int i = blockIdx.x * 256 + threadIdx.x;
    if (i >= N_NODES) return;
    int p = ptr[i] + bsum[blockIdx.x];
    ptr[i] = p;
    cursor[i] = p;
}

// spay[pos] = row | (r<<20)
__global__ void k_scatter(const int* __restrict__ row, const int* __restrict__ col,
                          int* __restrict__ cursor, int* __restrict__ spay) {
    int e = blockIdx.x * blockDim.x + threadIdx.x;
    if (e >= N_EDGES) return;
    int c = col[e];
    int pos = atomicAdd(cursor + c, 1);
    spay[pos] = row[e] | ((e / EPR) << 20);
}

// pull-aggregation: one wave per dst node, float2 per lane (128 outs), zero atomics
__global__ __launch_bounds__(256) void k_agg(const int* __restrict__ ptr,
                                             const int* __restrict__ cnt,
                                             const int* __restrict__ spay,
                                             const float* __restrict__ el,
                                             const float* __restrict__ er,
                                             const float* __restrict__ feat,
                                             const float* __restrict__ bias,
                                             float* __restrict__ out) {
    const int wv = threadIdx.x >> 6, lane = threadIdx.x & 63;
    const int n = blockIdx.x * 4 + wv;
    if (n >= N_NODES) return;
    const int start = ptr[n], len = cnt[n];
    const int h = lane >> 4; // o = lane*2 -> head = o>>5
    float accx = 0.f, accy = 0.f, den = 0.f;
#pragma unroll 2
    for (int j = 0; j < len; ++j) {
        int p = spay[start + j];
        int rw = p & 0xFFFFF, r = p >> 20;
        size_t rb = (size_t)r * N_NODES;
        float s = el[(rb + rw) * N_HEADS + h] + er[(rb + n) * N_HEADS + h];
        s = s > 0.f ? s : 0.2f * s;
        float w = __expf(s);
        float2 v = *(const float2*)(feat + (rb + rw) * OUT_FEAT + lane * 2);
        accx += w * v.x;
        accy += w * v.y;
        den += w;
    }
    float inv = (len > 0) ? 1.f / den : 0.f;
    int o = lane * 2;
    float2 res;
    res.x = accx * inv + bias[o];
    res.y = accy * inv + bias[o + 1];
    *(float2*)(out + (size_t)n * OUT_FEAT + o) = res;
}

extern "C" void kernel_launch(void* const* d_in, const int* in_sizes, int n_in,
                              void* d_out, int out_size, void* d_ws, size_t ws_size,
                              hipStream_t stream) {
    const float* x = (const float*)d_in[0];
    const float* cw = (const float*)d_in[1];
    const float* al = (const float*)d_in[2];
    const float* ar = (const float*)d_in[3];
    const float* bias = (const float*)d_in[4];
    const int* row = (const int*)d_in[5];
    const int* col = (const int*)d_in[6];
    float* out = (float*)d_out;
    float* ws = (float*)d_ws;

    float* feat = ws + OFF_FEAT;
    float* el = ws + OFF_EL;
    float* er = ws + OFF_ER;
    float* wb = ws + OFF_WB;
    __bf16* wt = (__bf16*)(ws + OFF_WT);
    int* iw = (int*)(ws + OFF_INT);
    int* cnt = iw + IOFF_CNT;
    int* ptr = iw + IOFF_PTR;
    int* cur = iw + IOFF_CUR;
    int* bsum = iw + IOFF_BSUM;
    int* spay = iw + IOFF_SPAY;

    hipMemsetAsync(cnt, 0, N_NODES * sizeof(int), stream);

    k_wboth<<<(IN_FEAT * 64 + 255) / 256, 256, 0, stream>>>(cw, al, ar, wb);
    k_cvt_w<<<(NUM_RELS * N_HEADS * IN_FEAT * HEAD_DIM + 255) / 256, 256, 0, stream>>>(cw, wt);
    k_tmfma<<<dim3((N_NODES + 127) / 128, NUM_RELS), 256, 0, stream>>>(x, wt, feat);
    k_elr<<<(N_NODES + 3) / 4, 256, 0, stream>>>(x, wb, el, er);

    k_hist<<<(N_EDGES + 255) / 256, 256, 0, stream>>>(col, cnt);
    k_scanA<<<NB_SCAN, 256, 0, stream>>>(cnt, ptr, bsum);
    k_scanB<<<1, 256, 0, stream>>>(bsum);
    k_scanC<<<NB_SCAN, 256, 0, stream>>>(ptr, cur, bsum);
    k_scatter<<<(N_EDGES + 255) / 256, 256, 0, stream>>>(row, col, cur, spay);

    k_agg<<<(N_NODES + 3) / 4, 256, 0, stream>>>(ptr, cnt, spay, el, er, feat, bias, out);
}

// Round 4
// 299.691 us; speedup vs baseline: 4.1144x; 1.2786x over previous
//
#include <hip/hip_runtime.h>
#include <hip/hip_bf16.h>

#define N_NODES 50000
#define N_EDGES 819200
#define NUM_RELS 8
#define EPR (N_EDGES / NUM_RELS) /* 102400 */
#define N_HEADS 4
#define IN_FEAT 256
#define OUT_FEAT 128
#define HEAD_DIM 32
#define NB_SCAN ((N_NODES + 255) / 256) /* 196 */

typedef __attribute__((ext_vector_type(8))) __bf16 bf16x8;
typedef __attribute__((ext_vector_type(4))) __bf16 bf16x4;
typedef __attribute__((ext_vector_type(4))) float f32x4;

// ---- workspace layout ----
// float region
#define SZ_FEAT ((size_t)NUM_RELS * N_NODES * OUT_FEAT) /* 51,200,000 */
#define SZ_EL ((size_t)NUM_RELS * N_NODES * N_HEADS)    /* 1,600,000 */
#define SZ_WB ((size_t)IN_FEAT * 64)                    /* region holds wbt bf16 (32KB) */
#define SZ_WT ((size_t)NUM_RELS * OUT_FEAT * IN_FEAT / 2)
#define OFF_FEAT ((size_t)0)
#define OFF_EL (OFF_FEAT + SZ_FEAT)
#define OFF_ER (OFF_EL + SZ_EL)
#define OFF_WB (OFF_ER + SZ_EL)
#define OFF_WT (OFF_WB + SZ_WB)
#define OFF_INT (OFF_WT + SZ_WT)
// int region (offsets in ints, from OFF_INT)
#define IOFF_CNT ((size_t)0)
#define IOFF_PTR ((size_t)N_NODES)
#define IOFF_CUR ((size_t)2 * N_NODES)
#define IOFF_BSUM ((size_t)3 * N_NODES)
#define IOFF_SPAY ((size_t)3 * N_NODES + 256)

// folded attention vectors, written transposed bf16: wbt[col][k], col = side*32+r*4+h
__global__ void k_wboth(const float* __restrict__ cw, const float* __restrict__ al,
                        const float* __restrict__ ar, __bf16* __restrict__ wbt) {
    int tid = blockIdx.x * blockDim.x + threadIdx.x; // 16384 total
    if (tid >= IN_FEAT * 64) return;
    int col = tid >> 8, i = tid & 255; // i = k index (coalesced along k)
    int side = col >> 5, r = (col >> 2) & 7, h = col & 3;
    const float* av = (side ? ar : al) + (size_t)(r * N_HEADS + h) * HEAD_DIM;
    const float* cwp = cw + ((size_t)(r * N_HEADS + h) * IN_FEAT + i) * HEAD_DIM;
    float s = 0.f;
#pragma unroll
    for (int d = 0; d < HEAD_DIM; ++d) s += cwp[d] * av[d];
    wbt[(size_t)col * IN_FEAT + i] = (__bf16)s;
}

// wt[r][o][k] = bf16(cw[r][h][k][d]), o = h*32+d  -> B-operand k-contiguous
__global__ void k_cvt_w(const float* __restrict__ cw, __bf16* __restrict__ wt) {
    int tid = blockIdx.x * blockDim.x + threadIdx.x;
    if (tid >= NUM_RELS * N_HEADS * IN_FEAT * HEAD_DIM) return;
    int d = tid & 31, k = (tid >> 5) & 255, h = (tid >> 13) & 3, r = tid >> 15;
    float v = cw[tid];
    wt[((size_t)(r * OUT_FEAT + h * HEAD_DIM + d)) * IN_FEAT + k] = (__bf16)v;
}

// feat_all[r][n][o] = sum_k x[n][k]*W_r[k][o] via bf16 MFMA (fp32 accumulate)
__global__ __launch_bounds__(256) void k_tmfma(const float* __restrict__ x,
                                               const __bf16* __restrict__ wt,
                                               float* __restrict__ feat) {
    __shared__ __align__(16) unsigned char sA[16384]; // [128 rows][64 k] bf16 swizzled
    __shared__ __align__(16) unsigned char sB[16384]; // [128 o  ][64 k] bf16 swizzled
    const int t = threadIdx.x;
    const int lane = t & 63, w = t >> 6;
    const int n0 = blockIdx.x * 128;
    const int r = blockIdx.y;
    const int wr = w >> 1, wc = w & 1;

    f32x4 acc[4][4];
#pragma unroll
    for (int i = 0; i < 4; ++i)
#pragma unroll
        for (int j = 0; j < 4; ++j) acc[i][j] = (f32x4){0.f, 0.f, 0.f, 0.f};

    const __bf16* wtr = wt + (size_t)r * OUT_FEAT * IN_FEAT;

    for (int kc = 0; kc < 4; ++kc) {
#pragma unroll
        for (int i = 0; i < 8; ++i) {
            int flat = i * 64 + lane;
            int row = w * 32 + (flat >> 4);
            int kq = flat & 15;
            int nsrc = n0 + row;
            if (nsrc >= N_NODES) nsrc = N_NODES - 1;
            float4 v = *(const float4*)(x + (size_t)nsrc * IN_FEAT + kc * 64 + kq * 4);
            bf16x4 hv;
            hv[0] = (__bf16)v.x; hv[1] = (__bf16)v.y; hv[2] = (__bf16)v.z; hv[3] = (__bf16)v.w;
            int slot = (kq >> 1) ^ (row & 7);
            *(bf16x4*)(sA + row * 128 + slot * 16 + (kq & 1) * 8) = hv;
        }
#pragma unroll
        for (int i = 0; i < 4; ++i) {
            int flat = i * 64 + lane;
            int row = w * 32 + (flat >> 3);
            int s = flat & 7;
            int ssrc = s ^ (row & 7);
            bf16x8 v = *(const bf16x8*)(wtr + (size_t)row * IN_FEAT + kc * 64 + ssrc * 8);
            *(bf16x8*)(sB + row * 128 + s * 16) = v;
        }
        __syncthreads();
#pragma unroll
        for (int ks = 0; ks < 2; ++ks) {
            bf16x8 af[4], bg[4];
#pragma unroll
            for (int rb = 0; rb < 4; ++rb) {
                int row = wr * 64 + rb * 16 + (lane & 15);
                int slot = (ks * 4 + (lane >> 4)) ^ (row & 7);
                af[rb] = *(const bf16x8*)(sA + row * 128 + slot * 16);
            }
#pragma unroll
            for (int cb = 0; cb < 4; ++cb) {
                int row = wc * 64 + cb * 16 + (lane & 15);
                int slot = (ks * 4 + (lane >> 4)) ^ (row & 7);
                bg[cb] = *(const bf16x8*)(sB + row * 128 + slot * 16);
            }
#pragma unroll
            for (int rb = 0; rb < 4; ++rb)
#pragma unroll
                for (int cb = 0; cb < 4; ++cb)
                    acc[rb][cb] = __builtin_amdgcn_mfma_f32_16x16x32_bf16(af[rb], bg[cb], acc[rb][cb], 0, 0, 0);
        }
        __syncthreads();
    }
#pragma unroll
    for (int rb = 0; rb < 4; ++rb) {
#pragma unroll
        for (int q = 0; q < 4; ++q) {
            int row = wr * 64 + rb * 16 + (lane >> 4) * 4 + q;
            int n = n0 + row;
            if (n < N_NODES) {
                float* fp = feat + ((size_t)r * N_NODES + n) * OUT_FEAT + wc * 64 + (lane & 15);
#pragma unroll
                for (int cb = 0; cb < 4; ++cb) fp[cb * 16] = acc[rb][cb][q];
            }
        }
    }
}

// el/er for all (r,n,h) via MFMA: X[50000x256] @ wbt^T[256x64]
// 128-row x 64-col tile, 4 waves (wave w: rows w*32..+31), BK=64
__global__ __launch_bounds__(256) void k_elrm(const float* __restrict__ x,
                                              const __bf16* __restrict__ wbt,
                                              float* __restrict__ el,
                                              float* __restrict__ er) {
    __shared__ __align__(16) unsigned char sA[16384]; // [128 rows][64 k] bf16 swizzled
    __shared__ __align__(16) unsigned char sB[32768]; // [64 cols][256 k] bf16 swizzled
    const int t = threadIdx.x;
    const int lane = t & 63, w = t >> 6;
    const int n0 = blockIdx.x * 128;

    // stage sB once: 2048 16B slots, 32 slots/row, involution on low-3 slot bits
#pragma unroll
    for (int i = 0; i < 8; ++i) {
        int flat = i * 256 + t;
        int row = flat >> 5;   // col index 0..63
        int s = flat & 31;
        int ssrc = (s & ~7) | ((s & 7) ^ (row & 7));
        bf16x8 v = *(const bf16x8*)(wbt + (size_t)row * IN_FEAT + ssrc * 8);
        *(bf16x8*)(sB + row * 512 + s * 16) = v;
    }

    f32x4 acc[2][4];
#pragma unroll
    for (int i = 0; i < 2; ++i)
#pragma unroll
        for (int j = 0; j < 4; ++j) acc[i][j] = (f32x4){0.f, 0.f, 0.f, 0.f};

    for (int kc = 0; kc < 4; ++kc) {
        // stage sA chunk: 128 rows x 64 k (fp32 -> bf16)
#pragma unroll
        for (int i = 0; i < 8; ++i) {
            int flat = i * 256 + t;
            int row = flat >> 4;  // 0..127
            int kq = flat & 15;
            int n = n0 + row;
            if (n >= N_NODES) n = N_NODES - 1;
            float4 v = *(const float4*)(x + (size_t)n * IN_FEAT + kc * 64 + kq * 4);
            bf16x4 hv;
            hv[0] = (__bf16)v.x; hv[1] = (__bf16)v.y; hv[2] = (__bf16)v.z; hv[3] = (__bf16)v.w;
            int slot = (kq >> 1) ^ (row & 7);
            *(bf16x4*)(sA + row * 128 + slot * 16 + (kq & 1) * 8) = hv;
        }
        __syncthreads();
#pragma unroll
        for (int ks = 0; ks < 2; ++ks) {
            bf16x8 af[2], bg[4];
#pragma unroll
            for (int rb = 0; rb < 2; ++rb) {
                int row = w * 32 + rb * 16 + (lane & 15);
                int slot = (ks * 4 + (lane >> 4)) ^ (row & 7);
                af[rb] = *(const bf16x8*)(sA + row * 128 + slot * 16);
            }
#pragma unroll
            for (int cb = 0; cb < 4; ++cb) {
                int row = cb * 16 + (lane & 15);
                int slot = kc * 8 + ((ks * 4 + (lane >> 4)) ^ (row & 7));
                bg[cb] = *(const bf16x8*)(sB + row * 512 + slot * 16);
            }
#pragma unroll
            for (int rb = 0; rb < 2; ++rb)
#pragma unroll
                for (int cb = 0; cb < 4; ++cb)
                    acc[rb][cb] = __builtin_amdgcn_mfma_f32_16x16x32_bf16(af[rb], bg[cb], acc[rb][cb], 0, 0, 0);
        }
        __syncthreads();
    }
    // epilogue: col c -> (side, rr, h); write el/er[(rr*N+n)*4+h]
#pragma unroll
    for (int rb = 0; rb < 2; ++rb) {
#pragma unroll
        for (int q = 0; q < 4; ++q) {
            int n = n0 + w * 32 + rb * 16 + (lane >> 4) * 4 + q;
            if (n < N_NODES) {
#pragma unroll
                for (int cb = 0; cb < 4; ++cb) {
                    int c = cb * 16 + (lane & 15);
                    int side = c >> 5, rr = (c >> 2) & 7, h = c & 3;
                    float* dst = side ? er : el;
                    dst[((size_t)rr * N_NODES + n) * N_HEADS + h] = acc[rb][cb][q];
                }
            }
        }
    }
}

// ---- CSR build: histogram -> exclusive scan (2-level) -> scatter ----
__global__ void k_hist(const int* __restrict__ col, int* __restrict__ cnt) {
    int e = blockIdx.x * blockDim.x + threadIdx.x;
    if (e < N_EDGES) atomicAdd(cnt + col[e], 1);
}

__global__ __launch_bounds__(256) void k_scanA(const int* __restrict__ cnt,
                                               int* __restrict__ excl,
                                               int* __restrict__ bsum) {
    __shared__ int s[256];
    int i = blockIdx.x * 256 + threadIdx.x;
    int v = (i < N_NODES) ? cnt[i] : 0;
    s[threadIdx.x] = v;
    __syncthreads();
#pragma unroll
    for (int off = 1; off < 256; off <<= 1) {
        int t = (threadIdx.x >= off) ? s[threadIdx.x - off] : 0;
        __syncthreads();
        s[threadIdx.x] += t;
        __syncthreads();
    }
    if (i < N_NODES) excl[i] = s[threadIdx.x] - v;
    if (threadIdx.x == 255) bsum[blockIdx.x] = s[255];
}

__global__ __launch_bounds__(256) void k_scanB(int* __restrict__ bsum) {
    __shared__ int s[256];
    int v = (threadIdx.x < NB_SCAN) ? bsum[threadIdx.x] : 0;
    s[threadIdx.x] = v;
    __syncthreads();
#pragma unroll
    for (int off = 1; off < 256; off <<= 1) {
        int t = (threadIdx.x >= off) ? s[threadIdx.x - off] : 0;
        __syncthreads();
        s[threadIdx.x] += t;
        __syncthreads();
    }
    bsum[threadIdx.x] = s[threadIdx.x] - v; // exclusive
}

__global__ __launch_bounds__(256) void k_scanC(int* __restrict__ ptr,
                                               int* __restrict__ cursor,
                                               const int* __restrict__ bsum) {
    int i = blockIdx.x * 256 + threadIdx.x;
    if (i >= N_NODES) return;
    int p = ptr[i] + bsum[blockIdx.x];
    ptr[i] = p;
    cursor[i] = p;
}

// spay[pos] = row | (r<<20)
__global__ void k_scatter(const int* __restrict__ row, const int* __restrict__ col,
                          int* __restrict__ cursor, int* __restrict__ spay) {
    int e = blockIdx.x * blockDim.x + threadIdx.x;
    if (e >= N_EDGES) return;
    int c = col[e];
    int pos = atomicAdd(cursor + c, 1);
    spay[pos] = row[e] | ((e / EPR) << 20);
}

// pull-aggregation: one wave per dst node, float2 per lane (128 outs), zero atomics
__global__ __launch_bounds__(256) void k_agg(const int* __restrict__ ptr,
                                             const int* __restrict__ cnt,
                                             const int* __restrict__ spay,
                                             const float* __restrict__ el,
                                             const float* __restrict__ er,
                                             const float* __restrict__ feat,
                                             const float* __restrict__ bias,
                                             float* __restrict__ out) {
    const int wv = threadIdx.x >> 6, lane = threadIdx.x & 63;
    const int n = blockIdx.x * 4 + wv;
    if (n >= N_NODES) return;
    const int start = ptr[n], len = cnt[n];
    const int h = lane >> 4;
    float accx = 0.f, accy = 0.f, den = 0.f;
#pragma unroll 2
    for (int j = 0; j < len; ++j) {
        int p = spay[start + j];
        int rw = p & 0xFFFFF, r = p >> 20;
        size_t rb = (size_t)r * N_NODES;
        float s = el[(rb + rw) * N_HEADS + h] + er[(rb + n) * N_HEADS + h];
        s = s > 0.f ? s : 0.2f * s;
        float w = __expf(s);
        float2 v = *(const float2*)(feat + (rb + rw) * OUT_FEAT + lane * 2);
        accx += w * v.x;
        accy += w * v.y;
        den += w;
    }
    float inv = (len > 0) ? 1.f / den : 0.f;
    int o = lane * 2;
    float2 res;
    res.x = accx * inv + bias[o];
    res.y = accy * inv + bias[o + 1];
    *(float2*)(out + (size_t)n * OUT_FEAT + o) = res;
}

extern "C" void kernel_launch(void* const* d_in, const int* in_sizes, int n_in,
                              void* d_out, int out_size, void* d_ws, size_t ws_size,
                              hipStream_t stream) {
    const float* x = (const float*)d_in[0];
    const float* cw = (const float*)d_in[1];
    const float* al = (const float*)d_in[2];
    const float* ar = (const float*)d_in[3];
    const float* bias = (const float*)d_in[4];
    const int* row = (const int*)d_in[5];
    const int* col = (const int*)d_in[6];
    float* out = (float*)d_out;
    float* ws = (float*)d_ws;

    float* feat = ws + OFF_FEAT;
    float* el = ws + OFF_EL;
    float* er = ws + OFF_ER;
    __bf16* wbt = (__bf16*)(ws + OFF_WB);
    __bf16* wt = (__bf16*)(ws + OFF_WT);
    int* iw = (int*)(ws + OFF_INT);
    int* cnt = iw + IOFF_CNT;
    int* ptr = iw + IOFF_PTR;
    int* cur = iw + IOFF_CUR;
    int* bsum = iw + IOFF_BSUM;
    int* spay = iw + IOFF_SPAY;

    hipMemsetAsync(cnt, 0, N_NODES * sizeof(int), stream);

    k_wboth<<<(IN_FEAT * 64 + 255) / 256, 256, 0, stream>>>(cw, al, ar, wbt);
    k_cvt_w<<<(NUM_RELS * N_HEADS * IN_FEAT * HEAD_DIM + 255) / 256, 256, 0, stream>>>(cw, wt);
    k_tmfma<<<dim3((N_NODES + 127) / 128, NUM_RELS), 256, 0, stream>>>(x, wt, feat);
    k_elrm<<<(N_NODES + 127) / 128, 256, 0, stream>>>(x, wbt, el, er);

    k_hist<<<(N_EDGES + 255) / 256, 256, 0, stream>>>(col, cnt);
    k_scanA<<<NB_SCAN, 256, 0, stream>>>(cnt, ptr, bsum);
    k_scanB<<<1, 256, 0, stream>>>(bsum);
    k_scanC<<<NB_SCAN, 256, 0, stream>>>(ptr, cur, bsum);
    k_scatter<<<(N_EDGES + 255) / 256, 256, 0, stream>>>(row, col, cur, spay);

    k_agg<<<(N_NODES + 3) / 4, 256, 0, stream>>>(ptr, cnt, spay, el, er, feat, bias, out);
}

// Round 5
// 255.994 us; speedup vs baseline: 4.8168x; 1.1707x over previous
//
#include <hip/hip_runtime.h>
#include <hip/hip_bf16.h>

#define N_NODES 50000
#define N_EDGES 819200
#define NUM_RELS 8
#define EPR (N_EDGES / NUM_RELS) /* 102400 */
#define N_HEADS 4
#define IN_FEAT 256
#define OUT_FEAT 128
#define HEAD_DIM 32
#define NB_SCAN ((N_NODES + 255) / 256) /* 196 */

typedef __attribute__((ext_vector_type(8))) __bf16 bf16x8;
typedef __attribute__((ext_vector_type(4))) __bf16 bf16x4;
typedef __attribute__((ext_vector_type(4))) float f32x4;

// ---- workspace layout (float units; feat region now holds bf16, half-used) ----
#define SZ_FEAT ((size_t)NUM_RELS * N_NODES * OUT_FEAT)
#define SZ_EL ((size_t)NUM_RELS * N_NODES * N_HEADS)
#define SZ_WB ((size_t)IN_FEAT * 64)
#define SZ_WT ((size_t)NUM_RELS * OUT_FEAT * IN_FEAT / 2)
#define OFF_FEAT ((size_t)0)
#define OFF_EL (OFF_FEAT + SZ_FEAT)
#define OFF_ER (OFF_EL + SZ_EL)
#define OFF_WB (OFF_ER + SZ_EL)
#define OFF_WT (OFF_WB + SZ_WB)
#define OFF_INT (OFF_WT + SZ_WT)
#define IOFF_CNT ((size_t)0)
#define IOFF_PTR ((size_t)N_NODES)
#define IOFF_CUR ((size_t)2 * N_NODES)
#define IOFF_BSUM ((size_t)3 * N_NODES)
#define IOFF_SPAY ((size_t)3 * N_NODES + 256)

// folded attention vectors, transposed bf16: wbt[col][k], col = side*32+r*4+h
__global__ void k_wboth(const float* __restrict__ cw, const float* __restrict__ al,
                        const float* __restrict__ ar, __bf16* __restrict__ wbt) {
    int tid = blockIdx.x * blockDim.x + threadIdx.x;
    if (tid >= IN_FEAT * 64) return;
    int col = tid >> 8, i = tid & 255;
    int side = col >> 5, r = (col >> 2) & 7, h = col & 3;
    const float* av = (side ? ar : al) + (size_t)(r * N_HEADS + h) * HEAD_DIM;
    const float* cwp = cw + ((size_t)(r * N_HEADS + h) * IN_FEAT + i) * HEAD_DIM;
    float s = 0.f;
#pragma unroll
    for (int d = 0; d < HEAD_DIM; ++d) s += cwp[d] * av[d];
    wbt[(size_t)col * IN_FEAT + i] = (__bf16)s;
}

// wt[r][o][k] = bf16(cw[r][h][k][d]), o = h*32+d
__global__ void k_cvt_w(const float* __restrict__ cw, __bf16* __restrict__ wt) {
    int tid = blockIdx.x * blockDim.x + threadIdx.x;
    if (tid >= NUM_RELS * N_HEADS * IN_FEAT * HEAD_DIM) return;
    int d = tid & 31, k = (tid >> 5) & 255, h = (tid >> 13) & 3, r = tid >> 15;
    float v = cw[tid];
    wt[((size_t)(r * OUT_FEAT + h * HEAD_DIM + d)) * IN_FEAT + k] = (__bf16)v;
}

// feat_all[r][n][o] (bf16) = sum_k x[n][k]*W_r[k][o] via bf16 MFMA
__global__ __launch_bounds__(256) void k_tmfma(const float* __restrict__ x,
                                               const __bf16* __restrict__ wt,
                                               __bf16* __restrict__ featb) {
    __shared__ __align__(16) unsigned char sA[16384];
    __shared__ __align__(16) unsigned char sB[16384];
    const int t = threadIdx.x;
    const int lane = t & 63, w = t >> 6;
    const int n0 = blockIdx.x * 128;
    const int r = blockIdx.y;
    const int wr = w >> 1, wc = w & 1;

    f32x4 acc[4][4];
#pragma unroll
    for (int i = 0; i < 4; ++i)
#pragma unroll
        for (int j = 0; j < 4; ++j) acc[i][j] = (f32x4){0.f, 0.f, 0.f, 0.f};

    const __bf16* wtr = wt + (size_t)r * OUT_FEAT * IN_FEAT;

    for (int kc = 0; kc < 4; ++kc) {
#pragma unroll
        for (int i = 0; i < 8; ++i) {
            int flat = i * 64 + lane;
            int row = w * 32 + (flat >> 4);
            int kq = flat & 15;
            int nsrc = n0 + row;
            if (nsrc >= N_NODES) nsrc = N_NODES - 1;
            float4 v = *(const float4*)(x + (size_t)nsrc * IN_FEAT + kc * 64 + kq * 4);
            bf16x4 hv;
            hv[0] = (__bf16)v.x; hv[1] = (__bf16)v.y; hv[2] = (__bf16)v.z; hv[3] = (__bf16)v.w;
            int slot = (kq >> 1) ^ (row & 7);
            *(bf16x4*)(sA + row * 128 + slot * 16 + (kq & 1) * 8) = hv;
        }
#pragma unroll
        for (int i = 0; i < 4; ++i) {
            int flat = i * 64 + lane;
            int row = w * 32 + (flat >> 3);
            int s = flat & 7;
            int ssrc = s ^ (row & 7);
            bf16x8 v = *(const bf16x8*)(wtr + (size_t)row * IN_FEAT + kc * 64 + ssrc * 8);
            *(bf16x8*)(sB + row * 128 + s * 16) = v;
        }
        __syncthreads();
#pragma unroll
        for (int ks = 0; ks < 2; ++ks) {
            bf16x8 af[4], bg[4];
#pragma unroll
            for (int rb = 0; rb < 4; ++rb) {
                int row = wr * 64 + rb * 16 + (lane & 15);
                int slot = (ks * 4 + (lane >> 4)) ^ (row & 7);
                af[rb] = *(const bf16x8*)(sA + row * 128 + slot * 16);
            }
#pragma unroll
            for (int cb = 0; cb < 4; ++cb) {
                int row = wc * 64 + cb * 16 + (lane & 15);
                int slot = (ks * 4 + (lane >> 4)) ^ (row & 7);
                bg[cb] = *(const bf16x8*)(sB + row * 128 + slot * 16);
            }
#pragma unroll
            for (int rb = 0; rb < 4; ++rb)
#pragma unroll
                for (int cb = 0; cb < 4; ++cb)
                    acc[rb][cb] = __builtin_amdgcn_mfma_f32_16x16x32_bf16(af[rb], bg[cb], acc[rb][cb], 0, 0, 0);
        }
        __syncthreads();
    }
#pragma unroll
    for (int rb = 0; rb < 4; ++rb) {
#pragma unroll
        for (int q = 0; q < 4; ++q) {
            int row = wr * 64 + rb * 16 + (lane >> 4) * 4 + q;
            int n = n0 + row;
            if (n < N_NODES) {
                __bf16* fp = featb + ((size_t)r * N_NODES + n) * OUT_FEAT + wc * 64 + (lane & 15);
#pragma unroll
                for (int cb = 0; cb < 4; ++cb) fp[cb * 16] = (__bf16)acc[rb][cb][q];
            }
        }
    }
}

// el/er for all (r,n,h) via MFMA: X[50000x256] @ wbt^T[256x64]
__global__ __launch_bounds__(256) void k_elrm(const float* __restrict__ x,
                                              const __bf16* __restrict__ wbt,
                                              float* __restrict__ el,
                                              float* __restrict__ er) {
    __shared__ __align__(16) unsigned char sA[16384];
    __shared__ __align__(16) unsigned char sB[32768];
    const int t = threadIdx.x;
    const int lane = t & 63, w = t >> 6;
    const int n0 = blockIdx.x * 128;

#pragma unroll
    for (int i = 0; i < 8; ++i) {
        int flat = i * 256 + t;
        int row = flat >> 5;
        int s = flat & 31;
        int ssrc = (s & ~7) | ((s & 7) ^ (row & 7));
        bf16x8 v = *(const bf16x8*)(wbt + (size_t)row * IN_FEAT + ssrc * 8);
        *(bf16x8*)(sB + row * 512 + s * 16) = v;
    }

    f32x4 acc[2][4];
#pragma unroll
    for (int i = 0; i < 2; ++i)
#pragma unroll
        for (int j = 0; j < 4; ++j) acc[i][j] = (f32x4){0.f, 0.f, 0.f, 0.f};

    for (int kc = 0; kc < 4; ++kc) {
#pragma unroll
        for (int i = 0; i < 8; ++i) {
            int flat = i * 256 + t;
            int row = flat >> 4;
            int kq = flat & 15;
            int n = n0 + row;
            if (n >= N_NODES) n = N_NODES - 1;
            float4 v = *(const float4*)(x + (size_t)n * IN_FEAT + kc * 64 + kq * 4);
            bf16x4 hv;
            hv[0] = (__bf16)v.x; hv[1] = (__bf16)v.y; hv[2] = (__bf16)v.z; hv[3] = (__bf16)v.w;
            int slot = (kq >> 1) ^ (row & 7);
            *(bf16x4*)(sA + row * 128 + slot * 16 + (kq & 1) * 8) = hv;
        }
        __syncthreads();
#pragma unroll
        for (int ks = 0; ks < 2; ++ks) {
            bf16x8 af[2], bg[4];
#pragma unroll
            for (int rb = 0; rb < 2; ++rb) {
                int row = w * 32 + rb * 16 + (lane & 15);
                int slot = (ks * 4 + (lane >> 4)) ^ (row & 7);
                af[rb] = *(const bf16x8*)(sA + row * 128 + slot * 16);
            }
#pragma unroll
            for (int cb = 0; cb < 4; ++cb) {
                int row = cb * 16 + (lane & 15);
                int slot = kc * 8 + ((ks * 4 + (lane >> 4)) ^ (row & 7));
                bg[cb] = *(const bf16x8*)(sB + row * 512 + slot * 16);
            }
#pragma unroll
            for (int rb = 0; rb < 2; ++rb)
#pragma unroll
                for (int cb = 0; cb < 4; ++cb)
                    acc[rb][cb] = __builtin_amdgcn_mfma_f32_16x16x32_bf16(af[rb], bg[cb], acc[rb][cb], 0, 0, 0);
        }
        __syncthreads();
    }
#pragma unroll
    for (int rb = 0; rb < 2; ++rb) {
#pragma unroll
        for (int q = 0; q < 4; ++q) {
            int n = n0 + w * 32 + rb * 16 + (lane >> 4) * 4 + q;
            if (n < N_NODES) {
#pragma unroll
                for (int cb = 0; cb < 4; ++cb) {
                    int c = cb * 16 + (lane & 15);
                    int side = c >> 5, rr = (c >> 2) & 7, h = c & 3;
                    float* dst = side ? er : el;
                    dst[((size_t)rr * N_NODES + n) * N_HEADS + h] = acc[rb][cb][q];
                }
            }
        }
    }
}

// ---- CSR build ----
__global__ void k_hist(const int* __restrict__ col, int* __restrict__ cnt) {
    int e = blockIdx.x * blockDim.x + threadIdx.x;
    if (e < N_EDGES) atomicAdd(cnt + col[e], 1);
}

__global__ __launch_bounds__(256) void k_scanA(const int* __restrict__ cnt,
                                               int* __restrict__ excl,
                                               int* __restrict__ bsum) {
    __shared__ int s[256];
    int i = blockIdx.x * 256 + threadIdx.x;
    int v = (i < N_NODES) ? cnt[i] : 0;
    s[threadIdx.x] = v;
    __syncthreads();
#pragma unroll
    for (int off = 1; off < 256; off <<= 1) {
        int t = (threadIdx.x >= off) ? s[threadIdx.x - off] : 0;
        __syncthreads();
        s[threadIdx.x] += t;
        __syncthreads();
    }
    if (i < N_NODES) excl[i] = s[threadIdx.x] - v;
    if (threadIdx.x == 255) bsum[blockIdx.x] = s[255];
}

__global__ __launch_bounds__(256) void k_scanB(int* __restrict__ bsum) {
    __shared__ int s[256];
    int v = (threadIdx.x < NB_SCAN) ? bsum[threadIdx.x] : 0;
    s[threadIdx.x] = v;
    __syncthreads();
#pragma unroll
    for (int off = 1; off < 256; off <<= 1) {
        int t = (threadIdx.x >= off) ? s[threadIdx.x - off] : 0;
        __syncthreads();
        s[threadIdx.x] += t;
        __syncthreads();
    }
    bsum[threadIdx.x] = s[threadIdx.x] - v;
}

__global__ __launch_bounds__(256) void k_scanC(int* __restrict__ ptr,
                                               int* __restrict__ cursor,
                                               const int* __restrict__ bsum) {
    int i = blockIdx.x * 256 + threadIdx.x;
    if (i >= N_NODES) return;
    int p = ptr[i] + bsum[blockIdx.x];
    ptr[i] = p;
    cursor[i] = p;
}

__global__ void k_scatter(const int* __restrict__ row, const int* __restrict__ col,
                          int* __restrict__ cursor, int* __restrict__ spay) {
    int e = blockIdx.x * blockDim.x + threadIdx.x;
    if (e >= N_EDGES) return;
    int c = col[e];
    int pos = atomicAdd(cursor + c, 1);
    spay[pos] = row[e] | ((e / EPR) << 20);
}

// pull-aggregation, bf16 feat gather, 4-deep explicit pipeline
__global__ __launch_bounds__(256) void k_agg(const int* __restrict__ ptr,
                                             const int* __restrict__ cnt,
                                             const int* __restrict__ spay,
                                             const float* __restrict__ el,
                                             const float* __restrict__ er,
                                             const __bf16* __restrict__ featb,
                                             const float* __restrict__ bias,
                                             float* __restrict__ out) {
    const int wv = threadIdx.x >> 6, lane = threadIdx.x & 63;
    const int n = blockIdx.x * 4 + wv;
    if (n >= N_NODES) return;
    const int start = ptr[n], len = cnt[n];
    const int h = lane >> 4;
    float accx = 0.f, accy = 0.f, den = 0.f;
    int j = 0;
    for (; j + 4 <= len; j += 4) {
        int p[4];
#pragma unroll
        for (int u = 0; u < 4; ++u) p[u] = spay[start + j + u];
        float w[4], vx[4], vy[4];
#pragma unroll
        for (int u = 0; u < 4; ++u) {
            int rw = p[u] & 0xFFFFF, r = p[u] >> 20;
            size_t rb = (size_t)r * N_NODES;
            float s = el[(rb + rw) * N_HEADS + h] + er[(rb + n) * N_HEADS + h];
            s = s > 0.f ? s : 0.2f * s;
            w[u] = __expf(s);
            ushort2 raw = *(const ushort2*)(featb + (rb + rw) * OUT_FEAT + lane * 2);
            vx[u] = __uint_as_float((unsigned)raw.x << 16);
            vy[u] = __uint_as_float((unsigned)raw.y << 16);
        }
#pragma unroll
        for (int u = 0; u < 4; ++u) {
            accx += w[u] * vx[u];
            accy += w[u] * vy[u];
            den += w[u];
        }
    }
    for (; j < len; ++j) {
        int p = spay[start + j];
        int rw = p & 0xFFFFF, r = p >> 20;
        size_t rb = (size_t)r * N_NODES;
        float s = el[(rb + rw) * N_HEADS + h] + er[(rb + n) * N_HEADS + h];
        s = s > 0.f ? s : 0.2f * s;
        float w = __expf(s);
        ushort2 raw = *(const ushort2*)(featb + (rb + rw) * OUT_FEAT + lane * 2);
        accx += w * __uint_as_float((unsigned)raw.x << 16);
        accy += w * __uint_as_float((unsigned)raw.y << 16);
        den += w;
    }
    float inv = (len > 0) ? 1.f / den : 0.f;
    int o = lane * 2;
    float2 res;
    res.x = accx * inv + bias[o];
    res.y = accy * inv + bias[o + 1];
    *(float2*)(out + (size_t)n * OUT_FEAT + o) = res;
}

extern "C" void kernel_launch(void* const* d_in, const int* in_sizes, int n_in,
                              void* d_out, int out_size, void* d_ws, size_t ws_size,
                              hipStream_t stream) {
    const float* x = (const float*)d_in[0];
    const float* cw = (const float*)d_in[1];
    const float* al = (const float*)d_in[2];
    const float* ar = (const float*)d_in[3];
    const float* bias = (const float*)d_in[4];
    const int* row = (const int*)d_in[5];
    const int* col = (const int*)d_in[6];
    float* out = (float*)d_out;
    float* ws = (float*)d_ws;

    __bf16* featb = (__bf16*)(ws + OFF_FEAT);
    float* el = ws + OFF_EL;
    float* er = ws + OFF_ER;
    __bf16* wbt = (__bf16*)(ws + OFF_WB);
    __bf16* wt = (__bf16*)(ws + OFF_WT);
    int* iw = (int*)(ws + OFF_INT);
    int* cnt = iw + IOFF_CNT;
    int* ptr = iw + IOFF_PTR;
    int* cur = iw + IOFF_CUR;
    int* bsum = iw + IOFF_BSUM;
    int* spay = iw + IOFF_SPAY;

    hipMemsetAsync(cnt, 0, N_NODES * sizeof(int), stream);

    k_wboth<<<(IN_FEAT * 64 + 255) / 256, 256, 0, stream>>>(cw, al, ar, wbt);
    k_cvt_w<<<(NUM_RELS * N_HEADS * IN_FEAT * HEAD_DIM + 255) / 256, 256, 0, stream>>>(cw, wt);
    k_tmfma<<<dim3((N_NODES + 127) / 128, NUM_RELS), 256, 0, stream>>>(x, wt, featb);
    k_elrm<<<(N_NODES + 127) / 128, 256, 0, stream>>>(x, wbt, el, er);

    k_hist<<<(N_EDGES + 255) / 256, 256, 0, stream>>>(col, cnt);
    k_scanA<<<NB_SCAN, 256, 0, stream>>>(cnt, ptr, bsum);
    k_scanB<<<1, 256, 0, stream>>>(bsum);
    k_scanC<<<NB_SCAN, 256, 0, stream>>>(ptr, cur, bsum);
    k_scatter<<<(N_EDGES + 255) / 256, 256, 0, stream>>>(row, col, cur, spay);

    k_agg<<<(N_NODES + 3) / 4, 256, 0, stream>>>(ptr, cnt, spay, el, er, featb, bias, out);
}

// Round 6
// 213.377 us; speedup vs baseline: 5.7788x; 1.1997x over previous
//
#include <hip/hip_runtime.h>
#include <hip/hip_bf16.h>

#define N_NODES 50000
#define N_EDGES 819200
#define NUM_RELS 8
#define EPR (N_EDGES / NUM_RELS) /* 102400 */
#define N_HEADS 4
#define IN_FEAT 256
#define OUT_FEAT 128
#define HEAD_DIM 32
#define NB_SCAN ((N_NODES + 255) / 256) /* 196 */

typedef __attribute__((ext_vector_type(8))) __bf16 bf16x8;
typedef __attribute__((ext_vector_type(4))) __bf16 bf16x4;
typedef __attribute__((ext_vector_type(4))) float f32x4;

// ---- workspace layout (float units; feat region holds bf16, half-used) ----
#define SZ_FEAT ((size_t)NUM_RELS * N_NODES * OUT_FEAT)
#define SZ_EL ((size_t)NUM_RELS * N_NODES * N_HEADS)
#define SZ_WB ((size_t)IN_FEAT * 64)
#define SZ_WT ((size_t)NUM_RELS * OUT_FEAT * IN_FEAT / 2)
#define OFF_FEAT ((size_t)0)
#define OFF_EL (OFF_FEAT + SZ_FEAT)
#define OFF_ER (OFF_EL + SZ_EL)
#define OFF_WB (OFF_ER + SZ_EL)
#define OFF_WT (OFF_WB + SZ_WB)
#define OFF_INT (OFF_WT + SZ_WT)
#define IOFF_CNT ((size_t)0)
#define IOFF_PTR ((size_t)N_NODES)
#define IOFF_CUR ((size_t)2 * N_NODES)
#define IOFF_BSUM ((size_t)3 * N_NODES)
#define IOFF_SPAY ((size_t)3 * N_NODES + 256)

// folded attention vectors, transposed bf16: wbt[col][k], col = side*32+r*4+h
__global__ void k_wboth(const float* __restrict__ cw, const float* __restrict__ al,
                        const float* __restrict__ ar, __bf16* __restrict__ wbt) {
    int tid = blockIdx.x * blockDim.x + threadIdx.x;
    if (tid >= IN_FEAT * 64) return;
    int col = tid >> 8, i = tid & 255;
    int side = col >> 5, r = (col >> 2) & 7, h = col & 3;
    const float* av = (side ? ar : al) + (size_t)(r * N_HEADS + h) * HEAD_DIM;
    const float* cwp = cw + ((size_t)(r * N_HEADS + h) * IN_FEAT + i) * HEAD_DIM;
    float s = 0.f;
#pragma unroll
    for (int d = 0; d < HEAD_DIM; ++d) s += cwp[d] * av[d];
    wbt[(size_t)col * IN_FEAT + i] = (__bf16)s;
}

// wt[r][o][k] = bf16(cw[r][h][k][d]), o = h*32+d
__global__ void k_cvt_w(const float* __restrict__ cw, __bf16* __restrict__ wt) {
    int tid = blockIdx.x * blockDim.x + threadIdx.x;
    if (tid >= NUM_RELS * N_HEADS * IN_FEAT * HEAD_DIM) return;
    int d = tid & 31, k = (tid >> 5) & 255, h = (tid >> 13) & 3, r = tid >> 15;
    float v = cw[tid];
    wt[((size_t)(r * OUT_FEAT + h * HEAD_DIM + d)) * IN_FEAT + k] = (__bf16)v;
}

// Fused: X staged once per 128-node tile (full K=256 bf16, swizzled), then
// 8 rel GEMM passes (feat) + 1 folded-attn pass (el/er). 4 waves as 2x2.
__global__ __launch_bounds__(256) void k_fused(const float* __restrict__ x,
                                               const __bf16* __restrict__ wt,
                                               const __bf16* __restrict__ wbt,
                                               __bf16* __restrict__ featb,
                                               float* __restrict__ el,
                                               float* __restrict__ er) {
    __shared__ __align__(16) unsigned char sA[65536]; // [128 rows][256 k] bf16, 512B/row, 32 slots
    __shared__ __align__(16) unsigned char sB[16384]; // [128 rows][64 k] bf16, 128B/row, 8 slots
    const int t = threadIdx.x;
    const int lane = t & 63;
    const int w = t >> 6;
    const int wr = w >> 1, wc = w & 1;
    const int n0 = blockIdx.x * 128;

    // ---- stage A once: 128 rows x 256 k, fp32 -> bf16, swizzled ----
#pragma unroll 8
    for (int i = 0; i < 32; ++i) {
        int flat = i * 256 + t;       // 0..8191 (half-slots: float4 -> 8B)
        int row = flat >> 6;          // 0..127
        int kq = flat & 63;           // k = kq*4
        int n = n0 + row;
        if (n >= N_NODES) n = N_NODES - 1;
        float4 v = *(const float4*)(x + (size_t)n * IN_FEAT + kq * 4);
        bf16x4 hv;
        hv[0] = (__bf16)v.x; hv[1] = (__bf16)v.y; hv[2] = (__bf16)v.z; hv[3] = (__bf16)v.w;
        int sg = kq >> 1; // 16B slot 0..31
        int slot = (sg & ~7) | ((sg & 7) ^ (row & 7));
        *(bf16x4*)(sA + row * 512 + slot * 16 + (kq & 1) * 8) = hv;
    }
    __syncthreads();

    f32x4 acc[4][4];

    // ---- 8 relation passes ----
    for (int r = 0; r < NUM_RELS; ++r) {
#pragma unroll
        for (int i = 0; i < 4; ++i)
#pragma unroll
            for (int j = 0; j < 4; ++j) acc[i][j] = (f32x4){0.f, 0.f, 0.f, 0.f};
        const __bf16* wtr = wt + (size_t)r * OUT_FEAT * IN_FEAT;

        for (int kc = 0; kc < 4; ++kc) {
            // stage B chunk: 128 out-rows x 64 k
#pragma unroll
            for (int i = 0; i < 4; ++i) {
                int flat = i * 256 + t;   // 0..1023
                int brow = flat >> 3;     // 0..127
                int s = flat & 7;
                int ssrc = s ^ (brow & 7);
                bf16x8 v = *(const bf16x8*)(wtr + (size_t)brow * IN_FEAT + kc * 64 + ssrc * 8);
                *(bf16x8*)(sB + brow * 128 + s * 16) = v;
            }
            __syncthreads();
#pragma unroll
            for (int ks = 0; ks < 2; ++ks) {
                bf16x8 af[4], bg[4];
#pragma unroll
                for (int rb = 0; rb < 4; ++rb) {
                    int row = wr * 64 + rb * 16 + (lane & 15);
                    int slot = kc * 8 + ((ks * 4 + (lane >> 4)) ^ (row & 7));
                    af[rb] = *(const bf16x8*)(sA + row * 512 + slot * 16);
                }
#pragma unroll
                for (int cb = 0; cb < 4; ++cb) {
                    int brow = wc * 64 + cb * 16 + (lane & 15);
                    int slot = (ks * 4 + (lane >> 4)) ^ (brow & 7);
                    bg[cb] = *(const bf16x8*)(sB + brow * 128 + slot * 16);
                }
#pragma unroll
                for (int rb = 0; rb < 4; ++rb)
#pragma unroll
                    for (int cb = 0; cb < 4; ++cb)
                        acc[rb][cb] = __builtin_amdgcn_mfma_f32_16x16x32_bf16(af[rb], bg[cb], acc[rb][cb], 0, 0, 0);
            }
            __syncthreads();
        }
        // epilogue rel r (C map: col=lane&15, row=(lane>>4)*4+q)
#pragma unroll
        for (int rb = 0; rb < 4; ++rb) {
#pragma unroll
            for (int q = 0; q < 4; ++q) {
                int row = wr * 64 + rb * 16 + (lane >> 4) * 4 + q;
                int n = n0 + row;
                if (n < N_NODES) {
                    __bf16* fp = featb + ((size_t)r * N_NODES + n) * OUT_FEAT + wc * 64 + (lane & 15);
#pragma unroll
                    for (int cb = 0; cb < 4; ++cb) fp[cb * 16] = (__bf16)acc[rb][cb][q];
                }
            }
        }
    }

    // ---- el/er pass: B = wbt[64 cols][256 k]; waves tile 128 rows x 64 cols ----
#pragma unroll
    for (int i = 0; i < 4; ++i)
#pragma unroll
        for (int j = 0; j < 2; ++j) acc[i][j] = (f32x4){0.f, 0.f, 0.f, 0.f};

    for (int kc = 0; kc < 4; ++kc) {
#pragma unroll
        for (int i = 0; i < 2; ++i) {
            int flat = i * 256 + t;   // 0..511
            int brow = flat >> 3;     // 0..63
            int s = flat & 7;
            int ssrc = s ^ (brow & 7);
            bf16x8 v = *(const bf16x8*)(wbt + (size_t)brow * IN_FEAT + kc * 64 + ssrc * 8);
            *(bf16x8*)(sB + brow * 128 + s * 16) = v;
        }
        __syncthreads();
#pragma unroll
        for (int ks = 0; ks < 2; ++ks) {
            bf16x8 af[4], bg[2];
#pragma unroll
            for (int rb = 0; rb < 4; ++rb) {
                int row = wr * 64 + rb * 16 + (lane & 15);
                int slot = kc * 8 + ((ks * 4 + (lane >> 4)) ^ (row & 7));
                af[rb] = *(const bf16x8*)(sA + row * 512 + slot * 16);
            }
#pragma unroll
            for (int cb = 0; cb < 2; ++cb) {
                int brow = wc * 32 + cb * 16 + (lane & 15);
                int slot = (ks * 4 + (lane >> 4)) ^ (brow & 7);
                bg[cb] = *(const bf16x8*)(sB + brow * 128 + slot * 16);
            }
#pragma unroll
            for (int rb = 0; rb < 4; ++rb)
#pragma unroll
                for (int cb = 0; cb < 2; ++cb)
                    acc[rb][cb] = __builtin_amdgcn_mfma_f32_16x16x32_bf16(af[rb], bg[cb], acc[rb][cb], 0, 0, 0);
        }
        __syncthreads();
    }
#pragma unroll
    for (int rb = 0; rb < 4; ++rb) {
#pragma unroll
        for (int q = 0; q < 4; ++q) {
            int n = n0 + wr * 64 + rb * 16 + (lane >> 4) * 4 + q;
            if (n < N_NODES) {
#pragma unroll
                for (int cb = 0; cb < 2; ++cb) {
                    int c = wc * 32 + cb * 16 + (lane & 15);
                    int side = c >> 5, rr = (c >> 2) & 7, h = c & 3;
                    float* dst = side ? er : el;
                    dst[((size_t)rr * N_NODES + n) * N_HEADS + h] = acc[rb][cb][q];
                }
            }
        }
    }
}

// ---- CSR build ----
__global__ void k_hist(const int* __restrict__ col, int* __restrict__ cnt) {
    int e = blockIdx.x * blockDim.x + threadIdx.x;
    if (e < N_EDGES) atomicAdd(cnt + col[e], 1);
}

__global__ __launch_bounds__(256) void k_scanA(const int* __restrict__ cnt,
                                               int* __restrict__ excl,
                                               int* __restrict__ bsum) {
    __shared__ int s[256];
    int i = blockIdx.x * 256 + threadIdx.x;
    int v = (i < N_NODES) ? cnt[i] : 0;
    s[threadIdx.x] = v;
    __syncthreads();
#pragma unroll
    for (int off = 1; off < 256; off <<= 1) {
        int t = (threadIdx.x >= off) ? s[threadIdx.x - off] : 0;
        __syncthreads();
        s[threadIdx.x] += t;
        __syncthreads();
    }
    if (i < N_NODES) excl[i] = s[threadIdx.x] - v;
    if (threadIdx.x == 255) bsum[blockIdx.x] = s[255];
}

__global__ __launch_bounds__(256) void k_scanB(int* __restrict__ bsum) {
    __shared__ int s[256];
    int v = (threadIdx.x < NB_SCAN) ? bsum[threadIdx.x] : 0;
    s[threadIdx.x] = v;
    __syncthreads();
#pragma unroll
    for (int off = 1; off < 256; off <<= 1) {
        int t = (threadIdx.x >= off) ? s[threadIdx.x - off] : 0;
        __syncthreads();
        s[threadIdx.x] += t;
        __syncthreads();
    }
    bsum[threadIdx.x] = s[threadIdx.x] - v;
}

__global__ __launch_bounds__(256) void k_scanC(int* __restrict__ ptr,
                                               int* __restrict__ cursor,
                                               const int* __restrict__ bsum) {
    int i = blockIdx.x * 256 + threadIdx.x;
    if (i >= N_NODES) return;
    int p = ptr[i] + bsum[blockIdx.x];
    ptr[i] = p;
    cursor[i] = p;
}

__global__ void k_scatter(const int* __restrict__ row, const int* __restrict__ col,
                          int* __restrict__ cursor, int* __restrict__ spay) {
    int e = blockIdx.x * blockDim.x + threadIdx.x;
    if (e >= N_EDGES) return;
    int c = col[e];
    int pos = atomicAdd(cursor + c, 1);
    spay[pos] = row[e] | ((e / EPR) << 20);
}

// pull-aggregation, bf16 feat gather, 4-deep explicit pipeline
__global__ __launch_bounds__(256) void k_agg(const int* __restrict__ ptr,
                                             const int* __restrict__ cnt,
                                             const int* __restrict__ spay,
                                             const float* __restrict__ el,
                                             const float* __restrict__ er,
                                             const __bf16* __restrict__ featb,
                                             const float* __restrict__ bias,
                                             float* __restrict__ out) {
    const int wv = threadIdx.x >> 6, lane = threadIdx.x & 63;
    const int n = blockIdx.x * 4 + wv;
    if (n >= N_NODES) return;
    const int start = ptr[n], len = cnt[n];
    const int h = lane >> 4;
    float accx = 0.f, accy = 0.f, den = 0.f;
    int j = 0;
    for (; j + 4 <= len; j += 4) {
        int p[4];
#pragma unroll
        for (int u = 0; u < 4; ++u) p[u] = spay[start + j + u];
        float w[4], vx[4], vy[4];
#pragma unroll
        for (int u = 0; u < 4; ++u) {
            int rw = p[u] & 0xFFFFF, r = p[u] >> 20;
            size_t rb = (size_t)r * N_NODES;
            float s = el[(rb + rw) * N_HEADS + h] + er[(rb + n) * N_HEADS + h];
            s = s > 0.f ? s : 0.2f * s;
            w[u] = __expf(s);
            ushort2 raw = *(const ushort2*)(featb + (rb + rw) * OUT_FEAT + lane * 2);
            vx[u] = __uint_as_float((unsigned)raw.x << 16);
            vy[u] = __uint_as_float((unsigned)raw.y << 16);
        }
#pragma unroll
        for (int u = 0; u < 4; ++u) {
            accx += w[u] * vx[u];
            accy += w[u] * vy[u];
            den += w[u];
        }
    }
    for (; j < len; ++j) {
        int p = spay[start + j];
        int rw = p & 0xFFFFF, r = p >> 20;
        size_t rb = (size_t)r * N_NODES;
        float s = el[(rb + rw) * N_HEADS + h] + er[(rb + n) * N_HEADS + h];
        s = s > 0.f ? s : 0.2f * s;
        float w = __expf(s);
        ushort2 raw = *(const ushort2*)(featb + (rb + rw) * OUT_FEAT + lane * 2);
        accx += w * __uint_as_float((unsigned)raw.x << 16);
        accy += w * __uint_as_float((unsigned)raw.y << 16);
        den += w;
    }
    float inv = (len > 0) ? 1.f / den : 0.f;
    int o = lane * 2;
    float2 res;
    res.x = accx * inv + bias[o];
    res.y = accy * inv + bias[o + 1];
    *(float2*)(out + (size_t)n * OUT_FEAT + o) = res;
}

extern "C" void kernel_launch(void* const* d_in, const int* in_sizes, int n_in,
                              void* d_out, int out_size, void* d_ws, size_t ws_size,
                              hipStream_t stream) {
    const float* x = (const float*)d_in[0];
    const float* cw = (const float*)d_in[1];
    const float* al = (const float*)d_in[2];
    const float* ar = (const float*)d_in[3];
    const float* bias = (const float*)d_in[4];
    const int* row = (const int*)d_in[5];
    const int* col = (const int*)d_in[6];
    float* out = (float*)d_out;
    float* ws = (float*)d_ws;

    __bf16* featb = (__bf16*)(ws + OFF_FEAT);
    float* el = ws + OFF_EL;
    float* er = ws + OFF_ER;
    __bf16* wbt = (__bf16*)(ws + OFF_WB);
    __bf16* wt = (__bf16*)(ws + OFF_WT);
    int* iw = (int*)(ws + OFF_INT);
    int* cnt = iw + IOFF_CNT;
    int* ptr = iw + IOFF_PTR;
    int* cur = iw + IOFF_CUR;
    int* bsum = iw + IOFF_BSUM;
    int* spay = iw + IOFF_SPAY;

    hipMemsetAsync(cnt, 0, N_NODES * sizeof(int), stream);

    k_wboth<<<(IN_FEAT * 64 + 255) / 256, 256, 0, stream>>>(cw, al, ar, wbt);
    k_cvt_w<<<(NUM_RELS * N_HEADS * IN_FEAT * HEAD_DIM + 255) / 256, 256, 0, stream>>>(cw, wt);
    k_fused<<<(N_NODES + 127) / 128, 256, 0, stream>>>(x, wt, wbt, featb, el, er);

    k_hist<<<(N_EDGES + 255) / 256, 256, 0, stream>>>(col, cnt);
    k_scanA<<<NB_SCAN, 256, 0, stream>>>(cnt, ptr, bsum);
    k_scanB<<<1, 256, 0, stream>>>(bsum);
    k_scanC<<<NB_SCAN, 256, 0, stream>>>(ptr, cur, bsum);
    k_scatter<<<(N_EDGES + 255) / 256, 256, 0, stream>>>(row, col, cur, spay);

    k_agg<<<(N_NODES + 3) / 4, 256, 0, stream>>>(ptr, cnt, spay, el, er, featb, bias, out);
}